// Round 6
// baseline (575.704 us; speedup 1.0000x reference)
//
#include <hip/hip_runtime.h>
#include <hip/hip_bf16.h>

typedef __hip_bfloat16 bf16;
typedef __bf16 b16x8 __attribute__((ext_vector_type(8)));
typedef float f32x4 __attribute__((ext_vector_type(4)));

#define HWs   12800   // 80*160
#define NPIX  25600   // 2*80*160
#define IMG_H 80
#define IMG_W 160

// load 8 consecutive f32 weights, convert to bf16 fragment (32B-aligned source)
static __device__ inline b16x8 load_w8(const float* p)
{
    const float4* q = (const float4*)p;
    float4 a = q[0], b = q[1];
    b16x8 r;
    r[0] = (__bf16)a.x; r[1] = (__bf16)a.y; r[2] = (__bf16)a.z; r[3] = (__bf16)a.w;
    r[4] = (__bf16)b.x; r[5] = (__bf16)b.y; r[6] = (__bf16)b.z; r[7] = (__bf16)b.w;
    return r;
}

// LN phase: thread (p = t&63, cq = t>>6) loads 32 channels of pixel pixbase+p,
// reduces mean/var, writes bf16 tile (pitch 136).
static __device__ inline void ln_to_tile(
    const float* __restrict__ X, const float* __restrict__ gg, const float* __restrict__ bb,
    int pixbase, int t, bf16* tile_s, float (*red1)[64], float (*red2)[64])
{
    int p = t & 63;
    int cq = t >> 6;
    int b = pixbase / HWs;
    int hw = pixbase - b * HWs;
    const float* base = X + ((size_t)b * 128) * HWs + hw + p;
    float xv[32];
    float s1 = 0.f, s2 = 0.f;
#pragma unroll
    for (int j = 0; j < 32; j++) {
        int c = cq * 32 + j;
        float v = base[(size_t)c * HWs];
        xv[j] = v; s1 += v; s2 += v * v;
    }
    red1[cq][p] = s1; red2[cq][p] = s2;
    __syncthreads();
    float S1 = red1[0][p] + red1[1][p] + red1[2][p] + red1[3][p];
    float S2 = red2[0][p] + red2[1][p] + red2[2][p] + red2[3][p];
    float mean = S1 * (1.f / 128.f);
    float var  = fmaxf(S2 * (1.f / 128.f) - mean * mean, 0.f);
    float rstd = rsqrtf(var + 1e-5f);
#pragma unroll
    for (int j = 0; j < 32; j++) {
        int c = cq * 32 + j;
        float y = (xv[j] - mean) * rstd * gg[c] + bb[c];
        tile_s[p * 136 + c] = __float2bfloat16(y);
    }
    __syncthreads();
}

// ---------------- Kernel 1/2: fused LN + value GEMM (MFMA, K=128, O=128) ----------------
__global__ __launch_bounds__(256) void k_val(
    const float* __restrict__ X,
    const float* __restrict__ gg, const float* __restrict__ bb,
    const float* __restrict__ Wv, const float* __restrict__ Bv,
    bf16* __restrict__ val)
{
    __shared__ __align__(16) bf16 tile_s[64 * 136];
    __shared__ float red1[4][64];
    __shared__ float red2[4][64];
    int tile = blockIdx.x;           // 0..399
    int t = threadIdx.x;
    int pixbase = tile * 64;
    ln_to_tile(X, gg, bb, pixbase, t, tile_s, red1, red2);

    int wv = t >> 6;
    int lane = t & 63;
    int lrow = lane & 15;
    int lq = lane >> 4;
    const b16x8* arow = (const b16x8*)(tile_s + (wv * 16 + lrow) * 136);
    b16x8 af[4];
#pragma unroll
    for (int kk = 0; kk < 4; kk++) af[kk] = arow[kk * 4 + lq];
#pragma unroll
    for (int ot = 0; ot < 8; ot++) {
        int o = ot * 16 + lrow;
        const float* wrow = Wv + (size_t)o * 128;
        f32x4 acc = {0.f, 0.f, 0.f, 0.f};
#pragma unroll
        for (int kk = 0; kk < 4; kk++)
            acc = __builtin_amdgcn_mfma_f32_16x16x32_bf16(af[kk], load_w8(wrow + (kk * 4 + lq) * 8), acc, 0, 0, 0);
        float bias = Bv[o];
#pragma unroll
        for (int r = 0; r < 4; r++) {
            int pix = pixbase + wv * 16 + lq * 4 + r;   // C/D: row = lq*4+r, col = lrow
            val[(size_t)pix * 128 + o] = __float2bfloat16(acc[r] + bias);
        }
    }
}

// ---------------- Kernel 3: fused LN(match) + [wc|wg|kpc|kpg] GEMM + softmax + kp ----------------
__global__ __launch_bounds__(256) void k_match(
    const float* __restrict__ match,
    const float* __restrict__ gg, const float* __restrict__ bb,
    const float* __restrict__ wc_w, const float* __restrict__ wc_b,
    const float* __restrict__ wg_w, const float* __restrict__ wg_b,
    const float* __restrict__ kpc_w, const float* __restrict__ kpc_b,
    const float* __restrict__ kpg_w, const float* __restrict__ kpg_b,
    const float* __restrict__ anc_c, const float* __restrict__ anc_g,
    bf16* __restrict__ wts_g, float* __restrict__ coords_g,
    float* __restrict__ kp_out)
{
    __shared__ __align__(16) bf16 tile_s[64 * 136];
    __shared__ bf16 logit_s[64 * 144];
    __shared__ float offs_s[64 * 18];
    __shared__ float red1[4][64];
    __shared__ float red2[4][64];
    int tile = blockIdx.x;           // 0..399
    int t = threadIdx.x;
    int pixbase = tile * 64;
    ln_to_tile(match, gg, bb, pixbase, t, tile_s, red1, red2);

    int wv = t >> 6;
    int lane = t & 63;
    int lrow = lane & 15;
    int lq = lane >> 4;
    const b16x8* arow = (const b16x8*)(tile_s + (wv * 16 + lrow) * 136);
    b16x8 af[4];
#pragma unroll
    for (int kk = 0; kk < 4; kk++) af[kk] = arow[kk * 4 + lq];

    for (int ot = 0; ot < 11; ot++) {        // O = 162 padded to 176
        int o = ot * 16 + lrow;
        const float* wr; float bias;
        if (o < 72)       { wr = wc_w  + (size_t)o * 128;         bias = wc_b[o]; }
        else if (o < 144) { wr = wg_w  + (size_t)(o - 72) * 128;  bias = wg_b[o - 72]; }
        else if (o < 153) { wr = kpc_w + (size_t)(o - 144) * 128; bias = kpc_b[o - 144]; }
        else if (o < 162) { wr = kpg_w + (size_t)(o - 153) * 128; bias = kpg_b[o - 153]; }
        else              { wr = kpg_w + (size_t)8 * 128;         bias = 0.f; }
        f32x4 acc = {0.f, 0.f, 0.f, 0.f};
#pragma unroll
        for (int kk = 0; kk < 4; kk++)
            acc = __builtin_amdgcn_mfma_f32_16x16x32_bf16(af[kk], load_w8(wr + (kk * 4 + lq) * 8), acc, 0, 0, 0);
#pragma unroll
        for (int r = 0; r < 4; r++) {
            int row = wv * 16 + lq * 4 + r;        // pixel within tile
            float v = acc[r] + bias;
            if (o < 144)       logit_s[row * 144 + o] = __float2bfloat16(v);
            else if (o < 162)  offs_s[row * 18 + (o - 144)] = v;
        }
    }
    __syncthreads();

    // softmax over P per (pixel, branch, group): 1024 tasks
#pragma unroll
    for (int i = 0; i < 4; i++) {
        int task = t + 256 * i;
        int lp = task >> 4;
        int sub = task & 15;
        int br = sub >> 3;
        int g = sub & 7;
        const bf16* base = logit_s + lp * 144 + br * 72 + g;   // channel c = p*8+g
        float v[9];
        float m = -1e30f;
#pragma unroll
        for (int p = 0; p < 9; p++) { v[p] = __bfloat162float(base[p * 8]); m = fmaxf(m, v[p]); }
        float s = 0.f;
#pragma unroll
        for (int p = 0; p < 9; p++) { v[p] = __expf(v[p] - m); s += v[p]; }
        float inv = 1.f / s;
        int pix = pixbase + lp;
        bf16* wb = wts_g + ((size_t)pix * 2 + br) * 72 + g * 9;
#pragma unroll
        for (int p = 0; p < 9; p++) wb[p] = __float2bfloat16(v[p] * inv);
    }

    // keypoints + sample coords: 1152 tasks. kp_out is FLOAT32 (reference output dtype).
    for (int i = 0; i < 5; i++) {
        int task = t + 256 * i;
        if (task < 1152) {
            int lp = task / 18;
            int sub = task - lp * 18;
            int br = sub / 9;
            int p = sub - br * 9;
            int pix = pixbase + lp;
            float off = offs_s[lp * 18 + br * 9 + p];
            const float* anc = br ? anc_g : anc_c;
            float ax = anc[(size_t)pix * 18 + p * 2];
            float ay = anc[(size_t)pix * 18 + p * 2 + 1];
            float kx = ax + off;
            float* kpo = kp_out + (size_t)br * (NPIX * 18) + (size_t)pix * 18 + p * 2;
            kpo[0] = kx;
            kpo[1] = ay;
            float* cbp = coords_g + ((size_t)pix * 2 + br) * 18 + p * 2;
            cbp[0] = kx * 160.f - 0.5f;
            cbp[1] = ay * 80.f - 0.5f;
        }
    }
}

// ---------------- Kernel 4: bilinear gather + aggregate + final projection ----------------
__global__ __launch_bounds__(256) void k_agg_out(
    const bf16* __restrict__ ctx_val, const bf16* __restrict__ geo_val,
    const bf16* __restrict__ wts_g, const float* __restrict__ coords_g,
    const float* __restrict__ mask,
    const float* __restrict__ out_w, const float* __restrict__ out_b,
    float* __restrict__ out)
{
    __shared__ __align__(16) bf16 smem[64 * 264];
    int tile = blockIdx.x;       // 0..399
    int t = threadIdx.x;
    int wv = t >> 6;
    int lane = t & 63;
    int pixbase = tile * 64;
    int b = pixbase / HWs;       // uniform per block (tiles don't cross batch)
    int rowbase = b * HWs;
    int g = lane >> 3;           // group of channels 2*lane, 2*lane+1

    // ---- phase 1: aggregation, 32 sequential wave-tasks per wave ----
    for (int i = 0; i < 32; i++) {
        int task = wv * 32 + i;          // 0..127
        int lp = task >> 1;
        int br = task & 1;
        int pix = pixbase + lp;
        const bf16* val = br ? geo_val : ctx_val;
        const float* cb = coords_g + ((size_t)pix * 2 + br) * 18;
        const bf16* wb = wts_g + ((size_t)pix * 2 + br) * 72 + g * 9;
        float a0 = 0.f, a1 = 0.f;
        for (int p = 0; p < 9; p++) {
            float px = cb[p * 2];
            float py = cb[p * 2 + 1];
            float fx = floorf(px), fy = floorf(py);
            float dx = px - fx, dy = py - fy;
            int x0 = (int)fx, y0 = (int)fy;
            float wt = __bfloat162float(wb[p]);
            float s0 = 0.f, s1 = 0.f;
            float cw[4] = {(1.f - dx) * (1.f - dy), dx * (1.f - dy), (1.f - dx) * dy, dx * dy};
            int cx[4] = {x0, x0 + 1, x0, x0 + 1};
            int cy[4] = {y0, y0, y0 + 1, y0 + 1};
#pragma unroll
            for (int c4 = 0; c4 < 4; c4++) {
                int x = cx[c4], y = cy[c4];
                if (x >= 0 && x < IMG_W && y >= 0 && y < IMG_H) {   // wave-uniform branch
                    const __hip_bfloat162* vp = (const __hip_bfloat162*)
                        (val + (size_t)(rowbase + y * IMG_W + x) * 128 + lane * 2);
                    __hip_bfloat162 v2 = *vp;
                    s0 += cw[c4] * __bfloat162float(v2.x);
                    s1 += cw[c4] * __bfloat162float(v2.y);
                }
            }
            a0 += s0 * wt;
            a1 += s1 * wt;
        }
        if (br == 0) {
            float mv = mask[pix];
            a0 *= mv; a1 *= mv;
        }
        __hip_bfloat162 pk;
        pk.x = __float2bfloat16(a0);
        pk.y = __float2bfloat16(a1);
        *(__hip_bfloat162*)(smem + lp * 264 + br * 128 + lane * 2) = pk;
    }
    __syncthreads();

    // ---- phase 2: projection (K=256), wave wv owns pixels [wv*16, wv*16+16) ----
    int lrow = lane & 15;
    int lq = lane >> 4;
    const b16x8* arow = (const b16x8*)(smem + (wv * 16 + lrow) * 264);
    b16x8 af[8];
#pragma unroll
    for (int kk = 0; kk < 8; kk++) af[kk] = arow[kk * 4 + lq];
    int hwb = pixbase - b * HWs + wv * 16;
#pragma unroll
    for (int ot = 0; ot < 8; ot++) {
        int o = ot * 16 + lrow;
        const float* wrow = out_w + (size_t)o * 256;
        f32x4 acc = {0.f, 0.f, 0.f, 0.f};
#pragma unroll
        for (int kk = 0; kk < 8; kk++)
            acc = __builtin_amdgcn_mfma_f32_16x16x32_bf16(af[kk], load_w8(wrow + (kk * 4 + lq) * 8), acc, 0, 0, 0);
        float bias = out_b[o];
#pragma unroll
        for (int r = 0; r < 4; r++) {
            int hw = hwb + lq * 4 + r;
            out[(size_t)b * (128 * HWs) + (size_t)o * HWs + hw] = acc[r] + bias;   // f32 store
        }
    }
}

extern "C" void kernel_launch(void* const* d_in, const int* in_sizes, int n_in,
                              void* d_out, int out_size, void* d_ws, size_t ws_size,
                              hipStream_t stream)
{
    const float* mask      = (const float*)d_in[0];
    const float* match     = (const float*)d_in[1];
    const float* context   = (const float*)d_in[2];
    const float* geometric = (const float*)d_in[3];
    const float* anc_c     = (const float*)d_in[4];
    const float* anc_g     = (const float*)d_in[5];
    const float* ln_g  = (const float*)d_in[6];
    const float* ln_b  = (const float*)d_in[7];
    const float* lnc_g = (const float*)d_in[8];
    const float* lnc_b = (const float*)d_in[9];
    const float* lng_g = (const float*)d_in[10];
    const float* lng_b = (const float*)d_in[11];
    const float* wc_w  = (const float*)d_in[12];
    const float* wc_b  = (const float*)d_in[13];
    const float* wg_w  = (const float*)d_in[14];
    const float* wg_b  = (const float*)d_in[15];
    const float* vc_w  = (const float*)d_in[16];
    const float* vc_b  = (const float*)d_in[17];
    const float* vg_w  = (const float*)d_in[18];
    const float* vg_b  = (const float*)d_in[19];
    const float* out_w = (const float*)d_in[20];
    const float* out_b = (const float*)d_in[21];
    const float* kpc_w = (const float*)d_in[22];
    const float* kpc_b = (const float*)d_in[23];
    const float* kpg_w = (const float*)d_in[24];
    const float* kpg_b = (const float*)d_in[25];

    // Scratch: ctx_val -> d_ws (6.55 MB); geo_val -> dead `context` input buffer;
    // wts/coords -> dead `geometric` input buffer. Same-stream kernels serialize;
    // d_in is restored from pristine before every launch.
    bf16*  ctx_val  = (bf16*)d_ws;
    bf16*  geo_val  = (bf16*)context;
    bf16*  wts_g    = (bf16*)geometric;
    float* coords_g = (float*)((char*)geometric + 7372800);

    float* outp = (float*)d_out;
    float* kp_out = outp + (size_t)2 * 128 * HWs;   // outputs are FLOAT32 (ref dtype)

    k_val<<<400, 256, 0, stream>>>(context, lnc_g, lnc_b, vc_w, vc_b, ctx_val);
    k_val<<<400, 256, 0, stream>>>(geometric, lng_g, lng_b, vg_w, vg_b, geo_val);
    k_match<<<400, 256, 0, stream>>>(match, ln_g, ln_b,
                                     wc_w, wc_b, wg_w, wg_b,
                                     kpc_w, kpc_b, kpg_w, kpg_b,
                                     anc_c, anc_g,
                                     wts_g, coords_g, kp_out);
    k_agg_out<<<400, 256, 0, stream>>>(ctx_val, geo_val, wts_g, coords_g, mask,
                                       out_w, out_b, outp);
}

// Round 7
// 266.858 us; speedup vs baseline: 2.1573x; 2.1573x over previous
//
#include <hip/hip_runtime.h>
#include <hip/hip_bf16.h>

typedef __hip_bfloat16 bf16;
typedef __bf16 b16x8 __attribute__((ext_vector_type(8)));
typedef float f32x4 __attribute__((ext_vector_type(4)));

#define HWs   12800   // 80*160
#define NPIX  25600   // 2*80*160
#define IMG_H 80
#define IMG_W 160

// load 8 consecutive f32 weights, convert to bf16 fragment (32B-aligned source)
static __device__ inline b16x8 load_w8(const float* p)
{
    const float4* q = (const float4*)p;
    float4 a = q[0], b = q[1];
    b16x8 r;
    r[0] = (__bf16)a.x; r[1] = (__bf16)a.y; r[2] = (__bf16)a.z; r[3] = (__bf16)a.w;
    r[4] = (__bf16)b.x; r[5] = (__bf16)b.y; r[6] = (__bf16)b.z; r[7] = (__bf16)b.w;
    return r;
}

// LN for a 32-pixel tile: thread (p = t&31, cq = t>>5) loads 16 channels of
// pixel pixbase+p, reduces mean/var, writes bf16 tile (pitch 136).
static __device__ inline void ln32(
    const float* __restrict__ X, const float* __restrict__ gg, const float* __restrict__ bb,
    int pixbase, int t, bf16* tile_s, float (*red1)[32], float (*red2)[32])
{
    int p = t & 31;
    int cq = t >> 5;              // 0..7, 16 channels each
    int b = pixbase >= HWs;
    int hw = pixbase - b * HWs;
    const float* base = X + ((size_t)b * 128) * HWs + hw + p;
    float xv[16];
    float s1 = 0.f, s2 = 0.f;
#pragma unroll
    for (int j = 0; j < 16; j++) {
        int c = cq * 16 + j;
        float v = base[(size_t)c * HWs];
        xv[j] = v; s1 += v; s2 += v * v;
    }
    red1[cq][p] = s1; red2[cq][p] = s2;
    __syncthreads();
    float S1 = 0.f, S2 = 0.f;
#pragma unroll
    for (int q = 0; q < 8; q++) { S1 += red1[q][p]; S2 += red2[q][p]; }
    float mean = S1 * (1.f / 128.f);
    float var  = fmaxf(S2 * (1.f / 128.f) - mean * mean, 0.f);
    float rstd = rsqrtf(var + 1e-5f);
#pragma unroll
    for (int j = 0; j < 16; j++) {
        int c = cq * 16 + j;
        float y = (xv[j] - mean) * rstd * gg[c] + bb[c];
        tile_s[p * 136 + c] = __float2bfloat16(y);
    }
    __syncthreads();
}

// ---------------- fused LN + value GEMM (MFMA, K=128, O=128), 32-px tiles ----------------
__global__ __launch_bounds__(256) void k_val(
    const float* __restrict__ X,
    const float* __restrict__ gg, const float* __restrict__ bb,
    const float* __restrict__ Wv, const float* __restrict__ Bv,
    bf16* __restrict__ val)
{
    __shared__ __align__(16) bf16 tile_s[32 * 136];
    __shared__ float red1[8][32];
    __shared__ float red2[8][32];
    int t = threadIdx.x;
    int pixbase = blockIdx.x * 32;      // 800 blocks
    ln32(X, gg, bb, pixbase, t, tile_s, red1, red2);

    int wv = t >> 6;
    int lane = t & 63;
    int s = wv >> 1;                    // subtile: 16 pixels
    int h = wv & 1;                     // output-half parity
    int lrow = lane & 15;
    int lq = lane >> 4;
    const b16x8* arow = (const b16x8*)(tile_s + (s * 16 + lrow) * 136);
    b16x8 af[4];
#pragma unroll
    for (int kk = 0; kk < 4; kk++) af[kk] = arow[kk * 4 + lq];
#pragma unroll
    for (int i = 0; i < 4; i++) {
        int ot = h + 2 * i;
        int o = ot * 16 + lrow;
        const float* wrow = Wv + (size_t)o * 128;
        f32x4 acc = {0.f, 0.f, 0.f, 0.f};
#pragma unroll
        for (int kk = 0; kk < 4; kk++)
            acc = __builtin_amdgcn_mfma_f32_16x16x32_bf16(af[kk], load_w8(wrow + (kk * 4 + lq) * 8), acc, 0, 0, 0);
        float bias = Bv[o];
#pragma unroll
        for (int r = 0; r < 4; r++) {
            int pix = pixbase + s * 16 + lq * 4 + r;   // C/D: row = lq*4+r, col = lrow
            val[(size_t)pix * 128 + o] = __float2bfloat16(acc[r] + bias);
        }
    }
}

// ---------------- fused LN(match) + [wc|wg|kpc|kpg] GEMM + softmax + kp, 32-px tiles ----------------
__global__ __launch_bounds__(256) void k_match(
    const float* __restrict__ match,
    const float* __restrict__ gg, const float* __restrict__ bb,
    const float* __restrict__ wc_w, const float* __restrict__ wc_b,
    const float* __restrict__ wg_w, const float* __restrict__ wg_b,
    const float* __restrict__ kpc_w, const float* __restrict__ kpc_b,
    const float* __restrict__ kpg_w, const float* __restrict__ kpg_b,
    const float* __restrict__ anc_c, const float* __restrict__ anc_g,
    bf16* __restrict__ wts_g, float* __restrict__ coords_g,
    float* __restrict__ kp_out)
{
    __shared__ __align__(16) bf16 tile_s[32 * 136];
    __shared__ bf16 logit_s[32 * 144];
    __shared__ float offs_s[32 * 18];
    __shared__ float red1[8][32];
    __shared__ float red2[8][32];
    int t = threadIdx.x;
    int pixbase = blockIdx.x * 32;      // 800 blocks
    ln32(match, gg, bb, pixbase, t, tile_s, red1, red2);

    int wv = t >> 6;
    int lane = t & 63;
    int s = wv >> 1;
    int h = wv & 1;
    int lrow = lane & 15;
    int lq = lane >> 4;
    const b16x8* arow = (const b16x8*)(tile_s + (s * 16 + lrow) * 136);
    b16x8 af[4];
#pragma unroll
    for (int kk = 0; kk < 4; kk++) af[kk] = arow[kk * 4 + lq];

    for (int ot = h; ot < 11; ot += 2) {     // O = 162 padded to 176
        int o = ot * 16 + lrow;
        const float* wr; float bias;
        if (o < 72)       { wr = wc_w  + (size_t)o * 128;         bias = wc_b[o]; }
        else if (o < 144) { wr = wg_w  + (size_t)(o - 72) * 128;  bias = wg_b[o - 72]; }
        else if (o < 153) { wr = kpc_w + (size_t)(o - 144) * 128; bias = kpc_b[o - 144]; }
        else if (o < 162) { wr = kpg_w + (size_t)(o - 153) * 128; bias = kpg_b[o - 153]; }
        else              { wr = kpg_w + (size_t)8 * 128;         bias = 0.f; }
        f32x4 acc = {0.f, 0.f, 0.f, 0.f};
#pragma unroll
        for (int kk = 0; kk < 4; kk++)
            acc = __builtin_amdgcn_mfma_f32_16x16x32_bf16(af[kk], load_w8(wr + (kk * 4 + lq) * 8), acc, 0, 0, 0);
#pragma unroll
        for (int r = 0; r < 4; r++) {
            int row = s * 16 + lq * 4 + r;         // pixel within tile
            float v = acc[r] + bias;
            if (o < 144)       logit_s[row * 144 + o] = __float2bfloat16(v);
            else if (o < 162)  offs_s[row * 18 + (o - 144)] = v;
        }
    }
    __syncthreads();

    // softmax over P per (pixel, branch, group): 512 tasks
#pragma unroll
    for (int i = 0; i < 2; i++) {
        int task = t + 256 * i;
        int lp = task >> 4;
        int sub = task & 15;
        int br = sub >> 3;
        int g = sub & 7;
        const bf16* base = logit_s + lp * 144 + br * 72 + g;   // channel c = p*8+g
        float v[9];
        float m = -1e30f;
#pragma unroll
        for (int p = 0; p < 9; p++) { v[p] = __bfloat162float(base[p * 8]); m = fmaxf(m, v[p]); }
        float ssum = 0.f;
#pragma unroll
        for (int p = 0; p < 9; p++) { v[p] = __expf(v[p] - m); ssum += v[p]; }
        float inv = 1.f / ssum;
        int pix = pixbase + lp;
        bf16* wb = wts_g + ((size_t)pix * 2 + br) * 72 + g * 9;
#pragma unroll
        for (int p = 0; p < 9; p++) wb[p] = __float2bfloat16(v[p] * inv);
    }

    // keypoints + sample coords: 576 tasks (kp_out is f32, the reference dtype)
    for (int i = 0; i < 3; i++) {
        int task = t + 256 * i;
        if (task < 576) {
            int lp = task / 18;
            int sub = task - lp * 18;
            int br = sub / 9;
            int p = sub - br * 9;
            int pix = pixbase + lp;
            float off = offs_s[lp * 18 + br * 9 + p];
            const float* anc = br ? anc_g : anc_c;
            float ax = anc[(size_t)pix * 18 + p * 2];
            float ay = anc[(size_t)pix * 18 + p * 2 + 1];
            float kx = ax + off;
            float* kpo = kp_out + (size_t)br * (NPIX * 18) + (size_t)pix * 18 + p * 2;
            kpo[0] = kx;
            kpo[1] = ay;
            float* cbp = coords_g + ((size_t)pix * 2 + br) * 18 + p * 2;
            cbp[0] = kx * 160.f - 0.5f;
            cbp[1] = ay * 80.f - 0.5f;
        }
    }
}

// ---------------- bilinear gather + group-weighted aggregate ----------------
// Quarter-wave (16 lanes) per (pixel,branch) task; lane owns 8 channels (b16x8).
// 51200 tasks = 3200 blocks x 16 tasks.
__global__ __launch_bounds__(256) void k_agg(
    const bf16* __restrict__ ctx_val, const bf16* __restrict__ geo_val,
    const bf16* __restrict__ wts_g, const float* __restrict__ coords_g,
    const float* __restrict__ mask,
    bf16* __restrict__ aggf)
{
    int t = threadIdx.x;
    int wv = t >> 6;
    int lane = t & 63;
    int q = lane >> 4;           // quarter-wave = task slot
    int sub = lane & 15;         // channel octet within the 128-ch half-row
    int c0 = sub * 8;
    int g = sub >> 1;            // group = c/16

    int tk = blockIdx.x * 16 + wv * 4 + q;    // task = pix*2 + br
    int pix = tk >> 1;
    int br = tk & 1;
    int b = pix >= HWs;
    int rowbase = b * HWs;

    const bf16* val = br ? geo_val : ctx_val;
    const float* cb = coords_g + (size_t)tk * 18;
    const bf16* wb = wts_g + (size_t)tk * 72 + g * 9;

    float wtv[9];
#pragma unroll
    for (int p = 0; p < 9; p++) wtv[p] = __bfloat162float(wb[p]);

    float acc[8] = {0.f, 0.f, 0.f, 0.f, 0.f, 0.f, 0.f, 0.f};
    for (int p = 0; p < 9; p++) {
        float px = cb[p * 2];
        float py = cb[p * 2 + 1];
        float fx = floorf(px), fy = floorf(py);
        float dx = px - fx, dy = py - fy;
        int x0 = (int)fx, y0 = (int)fy;
        float wt = wtv[p];
#pragma unroll
        for (int c4 = 0; c4 < 4; c4++) {
            int xi = x0 + (c4 & 1);
            int yi = y0 + (c4 >> 1);
            bool ok = (xi >= 0) & (xi < IMG_W) & (yi >= 0) & (yi < IMG_H);
            int xc = min(max(xi, 0), IMG_W - 1);
            int yc = min(max(yi, 0), IMG_H - 1);
            float wx = (c4 & 1) ? dx : 1.f - dx;
            float wy = (c4 >> 1) ? dy : 1.f - dy;
            float wgt = ok ? wx * wy * wt : 0.f;
            b16x8 v = *(const b16x8*)(val + (size_t)(rowbase + yc * IMG_W + xc) * 128 + c0);
#pragma unroll
            for (int j = 0; j < 8; j++) acc[j] += wgt * (float)v[j];
        }
    }
    float mv = (br == 0) ? mask[pix] : 1.f;
    b16x8 pk;
#pragma unroll
    for (int j = 0; j < 8; j++) pk[j] = (__bf16)(acc[j] * mv);
    *(b16x8*)(aggf + (size_t)pix * 256 + br * 128 + c0) = pk;
}

// ---------------- final projection (MFMA, K=256) + transposed f32 store, 32-px tiles ----------------
__global__ __launch_bounds__(256) void k_gemm_out(
    const bf16* __restrict__ aggf,
    const float* __restrict__ out_w, const float* __restrict__ out_b,
    float* __restrict__ out)
{
    int t = threadIdx.x;
    int pixbase = blockIdx.x * 32;       // 800 blocks
    int wv = t >> 6;
    int lane = t & 63;
    int s = wv >> 1;
    int h = wv & 1;
    int lrow = lane & 15;
    int lq = lane >> 4;
    const b16x8* arow = (const b16x8*)(aggf + (size_t)(pixbase + s * 16 + lrow) * 256);
    b16x8 af[8];
#pragma unroll
    for (int kk = 0; kk < 8; kk++) af[kk] = arow[kk * 4 + lq];
    int b = pixbase >= HWs;
#pragma unroll
    for (int i = 0; i < 4; i++) {
        int ot = h + 2 * i;
        int o = ot * 16 + lrow;
        const float* wrow = out_w + (size_t)o * 256;
        f32x4 acc = {0.f, 0.f, 0.f, 0.f};
#pragma unroll
        for (int kk = 0; kk < 8; kk++)
            acc = __builtin_amdgcn_mfma_f32_16x16x32_bf16(af[kk], load_w8(wrow + (kk * 4 + lq) * 8), acc, 0, 0, 0);
        float bias = out_b[o];
#pragma unroll
        for (int r = 0; r < 4; r++) {
            int pix = pixbase + s * 16 + lq * 4 + r;
            int hw = pix - b * HWs;
            out[(size_t)b * (128 * HWs) + (size_t)o * HWs + hw] = acc[r] + bias;
        }
    }
}

extern "C" void kernel_launch(void* const* d_in, const int* in_sizes, int n_in,
                              void* d_out, int out_size, void* d_ws, size_t ws_size,
                              hipStream_t stream)
{
    const float* mask      = (const float*)d_in[0];
    const float* match     = (const float*)d_in[1];
    const float* context   = (const float*)d_in[2];
    const float* geometric = (const float*)d_in[3];
    const float* anc_c     = (const float*)d_in[4];
    const float* anc_g     = (const float*)d_in[5];
    const float* ln_g  = (const float*)d_in[6];
    const float* ln_b  = (const float*)d_in[7];
    const float* lnc_g = (const float*)d_in[8];
    const float* lnc_b = (const float*)d_in[9];
    const float* lng_g = (const float*)d_in[10];
    const float* lng_b = (const float*)d_in[11];
    const float* wc_w  = (const float*)d_in[12];
    const float* wc_b  = (const float*)d_in[13];
    const float* wg_w  = (const float*)d_in[14];
    const float* wg_b  = (const float*)d_in[15];
    const float* vc_w  = (const float*)d_in[16];
    const float* vc_b  = (const float*)d_in[17];
    const float* vg_w  = (const float*)d_in[18];
    const float* vg_b  = (const float*)d_in[19];
    const float* out_w = (const float*)d_in[20];
    const float* out_b = (const float*)d_in[21];
    const float* kpc_w = (const float*)d_in[22];
    const float* kpc_b = (const float*)d_in[23];
    const float* kpg_w = (const float*)d_in[24];
    const float* kpg_b = (const float*)d_in[25];

    // Scratch lifetimes (stream-serialized; d_in restored before every launch):
    //   ctx_val  -> d_ws (6.55 MB)                       [written by launch 1]
    //   geo_val  -> dead `context` buffer (13.1 MB)      [written by launch 2]
    //   wts/coords -> dead `geometric` buffer            [written by launch 3]
    //   aggf     -> dead `match` buffer (13.1 MB, exact) [written by launch 4]
    bf16*  ctx_val  = (bf16*)d_ws;
    bf16*  geo_val  = (bf16*)context;
    bf16*  wts_g    = (bf16*)geometric;
    float* coords_g = (float*)((char*)geometric + 7372800);
    bf16*  aggf     = (bf16*)match;

    float* outp = (float*)d_out;
    float* kp_out = outp + (size_t)2 * 128 * HWs;   // outputs are f32 (ref dtype)

    k_val<<<800, 256, 0, stream>>>(context, lnc_g, lnc_b, vc_w, vc_b, ctx_val);
    k_val<<<800, 256, 0, stream>>>(geometric, lng_g, lng_b, vg_w, vg_b, geo_val);
    k_match<<<800, 256, 0, stream>>>(match, ln_g, ln_b,
                                     wc_w, wc_b, wg_w, wg_b,
                                     kpc_w, kpc_b, kpg_w, kpg_b,
                                     anc_c, anc_g,
                                     wts_g, coords_g, kp_out);
    k_agg<<<3200, 256, 0, stream>>>(ctx_val, geo_val, wts_g, coords_g, mask, aggf);
    k_gemm_out<<<800, 256, 0, stream>>>(aggf, out_w, out_b, outp);
}

// Round 8
// 238.632 us; speedup vs baseline: 2.4125x; 1.1183x over previous
//
#include <hip/hip_runtime.h>
#include <hip/hip_bf16.h>

typedef __hip_bfloat16 bf16;
typedef __bf16 b16x8 __attribute__((ext_vector_type(8)));
typedef float f32x4 __attribute__((ext_vector_type(4)));

#define HWs   12800   // 80*160
#define NPIX  25600   // 2*80*160
#define IMG_H 80
#define IMG_W 160

// load 8 consecutive f32 weights, convert to bf16 fragment (32B-aligned source)
static __device__ inline b16x8 load_w8(const float* p)
{
    const float4* q = (const float4*)p;
    float4 a = q[0], b = q[1];
    b16x8 r;
    r[0] = (__bf16)a.x; r[1] = (__bf16)a.y; r[2] = (__bf16)a.z; r[3] = (__bf16)a.w;
    r[4] = (__bf16)b.x; r[5] = (__bf16)b.y; r[6] = (__bf16)b.z; r[7] = (__bf16)b.w;
    return r;
}

// ---------------- Stage 1: fused LN + GEMMs for all three tensors ----------------
// blocks [0,800): LN(context)+vc -> ctx_val ; [800,1600): LN(geometric)+vg -> geo_val ;
// [1600,2400): LN(match)+[wc|wg|kpc|kpg] -> softmax wts, kp coords, kp_out.
__global__ __launch_bounds__(256) void k_stage1(
    const float* __restrict__ match, const float* __restrict__ context, const float* __restrict__ geometric,
    const float* __restrict__ ln_g, const float* __restrict__ ln_b,
    const float* __restrict__ lnc_g, const float* __restrict__ lnc_b,
    const float* __restrict__ lng_g, const float* __restrict__ lng_b,
    const float* __restrict__ vc_w, const float* __restrict__ vc_b,
    const float* __restrict__ vg_w, const float* __restrict__ vg_b,
    const float* __restrict__ wc_w, const float* __restrict__ wc_b,
    const float* __restrict__ wg_w, const float* __restrict__ wg_b,
    const float* __restrict__ kpc_w, const float* __restrict__ kpc_b,
    const float* __restrict__ kpg_w, const float* __restrict__ kpg_b,
    const float* __restrict__ anc_c, const float* __restrict__ anc_g,
    bf16* __restrict__ ctx_val, bf16* __restrict__ geo_val,
    bf16* __restrict__ wts_g, float* __restrict__ coords_g,
    float* __restrict__ kp_out)
{
    __shared__ __align__(16) bf16 tile_s[32 * 136];
    __shared__ bf16 logit_s[32 * 144];
    __shared__ float offs_s[32 * 18];
    __shared__ float red1[8][32];
    __shared__ float red2[8][32];

    int bx = blockIdx.x;
    int seg = bx / 800;                  // 0 ctx, 1 geo, 2 match
    int tile = bx - seg * 800;
    int t = threadIdx.x;
    int pixbase = tile * 32;

    const float* X  = (seg == 0) ? context : (seg == 1) ? geometric : match;
    const float* gg = (seg == 0) ? lnc_g   : (seg == 1) ? lng_g     : ln_g;
    const float* bb = (seg == 0) ? lnc_b   : (seg == 1) ? lng_b     : ln_b;

    // ---- LN into tile_s ----
    {
        int p = t & 31;
        int cq = t >> 5;
        int b = pixbase >= HWs;
        int hw = pixbase - b * HWs;
        const float* base = X + ((size_t)b * 128) * HWs + hw + p;
        float xv[16];
        float s1 = 0.f, s2 = 0.f;
#pragma unroll
        for (int j = 0; j < 16; j++) {
            int c = cq * 16 + j;
            float v = base[(size_t)c * HWs];
            xv[j] = v; s1 += v; s2 += v * v;
        }
        red1[cq][p] = s1; red2[cq][p] = s2;
        __syncthreads();
        float S1 = 0.f, S2 = 0.f;
#pragma unroll
        for (int q = 0; q < 8; q++) { S1 += red1[q][p]; S2 += red2[q][p]; }
        float mean = S1 * (1.f / 128.f);
        float var  = fmaxf(S2 * (1.f / 128.f) - mean * mean, 0.f);
        float rstd = rsqrtf(var + 1e-5f);
#pragma unroll
        for (int j = 0; j < 16; j++) {
            int c = cq * 16 + j;
            float y = (xv[j] - mean) * rstd * gg[c] + bb[c];
            tile_s[p * 136 + c] = __float2bfloat16(y);
        }
        __syncthreads();
    }

    int wv = t >> 6;
    int lane = t & 63;
    int s = wv >> 1;                     // subtile: 16 pixels
    int h = wv & 1;                      // output-tile parity
    int lrow = lane & 15;
    int lq = lane >> 4;
    const b16x8* arow = (const b16x8*)(tile_s + (s * 16 + lrow) * 136);
    b16x8 af[4];
#pragma unroll
    for (int kk = 0; kk < 4; kk++) af[kk] = arow[kk * 4 + lq];

    if (seg < 2) {
        const float* Wv = (seg == 0) ? vc_w : vg_w;
        const float* Bv = (seg == 0) ? vc_b : vg_b;
        bf16* val = (seg == 0) ? ctx_val : geo_val;
#pragma unroll
        for (int i = 0; i < 4; i++) {
            int o = (h + 2 * i) * 16 + lrow;
            const float* wrow = Wv + (size_t)o * 128;
            f32x4 acc = {0.f, 0.f, 0.f, 0.f};
#pragma unroll
            for (int kk = 0; kk < 4; kk++)
                acc = __builtin_amdgcn_mfma_f32_16x16x32_bf16(af[kk], load_w8(wrow + (kk * 4 + lq) * 8), acc, 0, 0, 0);
            float bias = Bv[o];
#pragma unroll
            for (int r = 0; r < 4; r++) {
                int pix = pixbase + s * 16 + lq * 4 + r;    // C/D: row = lq*4+r, col = lrow
                val[(size_t)pix * 128 + o] = __float2bfloat16(acc[r] + bias);
            }
        }
        return;
    }

    // ---- seg == 2: match branch ----
    for (int ot = h; ot < 11; ot += 2) {     // O = 162 padded to 176
        int o = ot * 16 + lrow;
        const float* wr; float bias;
        if (o < 72)       { wr = wc_w  + (size_t)o * 128;         bias = wc_b[o]; }
        else if (o < 144) { wr = wg_w  + (size_t)(o - 72) * 128;  bias = wg_b[o - 72]; }
        else if (o < 153) { wr = kpc_w + (size_t)(o - 144) * 128; bias = kpc_b[o - 144]; }
        else if (o < 162) { wr = kpg_w + (size_t)(o - 153) * 128; bias = kpg_b[o - 153]; }
        else              { wr = kpg_w + (size_t)8 * 128;         bias = 0.f; }
        f32x4 acc = {0.f, 0.f, 0.f, 0.f};
#pragma unroll
        for (int kk = 0; kk < 4; kk++)
            acc = __builtin_amdgcn_mfma_f32_16x16x32_bf16(af[kk], load_w8(wr + (kk * 4 + lq) * 8), acc, 0, 0, 0);
#pragma unroll
        for (int r = 0; r < 4; r++) {
            int row = s * 16 + lq * 4 + r;
            float v = acc[r] + bias;
            if (o < 144)       logit_s[row * 144 + o] = __float2bfloat16(v);
            else if (o < 162)  offs_s[row * 18 + (o - 144)] = v;
        }
    }
    __syncthreads();

    // softmax over P per (pixel, branch, group): 512 tasks
#pragma unroll
    for (int i = 0; i < 2; i++) {
        int task = t + 256 * i;
        int lp = task >> 4;
        int sub = task & 15;
        int br = sub >> 3;
        int g = sub & 7;
        const bf16* base = logit_s + lp * 144 + br * 72 + g;   // channel c = p*8+g
        float v[9];
        float m = -1e30f;
#pragma unroll
        for (int p = 0; p < 9; p++) { v[p] = __bfloat162float(base[p * 8]); m = fmaxf(m, v[p]); }
        float ssum = 0.f;
#pragma unroll
        for (int p = 0; p < 9; p++) { v[p] = __expf(v[p] - m); ssum += v[p]; }
        float inv = 1.f / ssum;
        int pix = pixbase + lp;
        bf16* wb = wts_g + ((size_t)pix * 2 + br) * 72 + g * 9;
#pragma unroll
        for (int p = 0; p < 9; p++) wb[p] = __float2bfloat16(v[p] * inv);
    }

    // keypoints + sample coords: 576 tasks (kp_out is f32, the reference dtype)
    for (int i = 0; i < 3; i++) {
        int task = t + 256 * i;
        if (task < 576) {
            int lp = task / 18;
            int sub = task - lp * 18;
            int br = sub / 9;
            int p = sub - br * 9;
            int pix = pixbase + lp;
            float off = offs_s[lp * 18 + br * 9 + p];
            const float* anc = br ? anc_g : anc_c;
            float ax = anc[(size_t)pix * 18 + p * 2];
            float ay = anc[(size_t)pix * 18 + p * 2 + 1];
            float kx = ax + off;
            float* kpo = kp_out + (size_t)br * (NPIX * 18) + (size_t)pix * 18 + p * 2;
            kpo[0] = kx;
            kpo[1] = ay;
            float* cbp = coords_g + ((size_t)pix * 2 + br) * 18 + p * 2;
            cbp[0] = kx * 160.f - 0.5f;
            cbp[1] = ay * 80.f - 0.5f;
        }
    }
}

// ---------------- bilinear gather + group-weighted aggregate (XCD-partitioned) ----------------
// Quarter-wave (16 lanes) per (pixel,branch) task; lane owns 8 channels (b16x8).
// blockIdx&7 selects the XCD (round-robin dispatch heuristic); XCDs 0-3 take the
// ctx branch, 4-7 the geo branch, so each per-XCD L2 caches mostly ONE 6.55 MB map.
__global__ __launch_bounds__(256) void k_agg(
    const bf16* __restrict__ ctx_val, const bf16* __restrict__ geo_val,
    const bf16* __restrict__ wts_g, const float* __restrict__ coords_g,
    const float* __restrict__ mask,
    bf16* __restrict__ aggf)
{
    int t = threadIdx.x;
    int wv = t >> 6;
    int lane = t & 63;
    int q = lane >> 4;           // quarter-wave task slot
    int sub = lane & 15;         // channel octet
    int c0 = sub * 8;
    int g = sub >> 1;            // group = c/16

    int bx = blockIdx.x;         // 0..3199
    int xcd = bx & 7;
    int br = xcd >> 2;           // XCDs 0-3 -> ctx, 4-7 -> geo
    int grp = (bx >> 3) * 4 + (xcd & 3);      // 0..1599
    int pix = grp * 16 + wv * 4 + q;          // 0..25599
    int tk = pix * 2 + br;
    int b = pix >= HWs;
    int rowbase = b * HWs;

    const bf16* val = br ? geo_val : ctx_val;
    const float* cb = coords_g + (size_t)tk * 18;
    const bf16* wb = wts_g + (size_t)tk * 72 + g * 9;

    float wtv[9];
#pragma unroll
    for (int p = 0; p < 9; p++) wtv[p] = __bfloat162float(wb[p]);

    float acc[8] = {0.f, 0.f, 0.f, 0.f, 0.f, 0.f, 0.f, 0.f};
    for (int p = 0; p < 9; p++) {
        float px = cb[p * 2];
        float py = cb[p * 2 + 1];
        float fx = floorf(px), fy = floorf(py);
        float dx = px - fx, dy = py - fy;
        int x0 = (int)fx, y0 = (int)fy;
        float wt = wtv[p];
#pragma unroll
        for (int c4 = 0; c4 < 4; c4++) {
            int xi = x0 + (c4 & 1);
            int yi = y0 + (c4 >> 1);
            bool ok = (xi >= 0) & (xi < IMG_W) & (yi >= 0) & (yi < IMG_H);
            int xc = min(max(xi, 0), IMG_W - 1);
            int yc = min(max(yi, 0), IMG_H - 1);
            float wx = (c4 & 1) ? dx : 1.f - dx;
            float wy = (c4 >> 1) ? dy : 1.f - dy;
            float wgt = ok ? wx * wy * wt : 0.f;
            b16x8 v = *(const b16x8*)(val + (size_t)(rowbase + yc * IMG_W + xc) * 128 + c0);
#pragma unroll
            for (int j = 0; j < 8; j++) acc[j] += wgt * (float)v[j];
        }
    }
    float mv = (br == 0) ? mask[pix] : 1.f;
    b16x8 pk;
#pragma unroll
    for (int j = 0; j < 8; j++) pk[j] = (__bf16)(acc[j] * mv);
    *(b16x8*)(aggf + (size_t)pix * 256 + br * 128 + c0) = pk;
}

// ---------------- final projection (MFMA, K=256) + transposed f32 store ----------------
__global__ __launch_bounds__(256) void k_gemm_out(
    const bf16* __restrict__ aggf,
    const float* __restrict__ out_w, const float* __restrict__ out_b,
    float* __restrict__ out)
{
    int t = threadIdx.x;
    int pixbase = blockIdx.x * 32;       // 800 blocks
    int wv = t >> 6;
    int lane = t & 63;
    int s = wv >> 1;
    int h = wv & 1;
    int lrow = lane & 15;
    int lq = lane >> 4;
    const b16x8* arow = (const b16x8*)(aggf + (size_t)(pixbase + s * 16 + lrow) * 256);
    b16x8 af[8];
#pragma unroll
    for (int kk = 0; kk < 8; kk++) af[kk] = arow[kk * 4 + lq];
    int b = pixbase >= HWs;
#pragma unroll
    for (int i = 0; i < 4; i++) {
        int o = (h + 2 * i) * 16 + lrow;
        const float* wrow = out_w + (size_t)o * 256;
        f32x4 acc = {0.f, 0.f, 0.f, 0.f};
#pragma unroll
        for (int kk = 0; kk < 8; kk++)
            acc = __builtin_amdgcn_mfma_f32_16x16x32_bf16(af[kk], load_w8(wrow + (kk * 4 + lq) * 8), acc, 0, 0, 0);
        float bias = out_b[o];
#pragma unroll
        for (int r = 0; r < 4; r++) {
            int pix = pixbase + s * 16 + lq * 4 + r;
            int hw = pix - b * HWs;
            out[(size_t)b * (128 * HWs) + (size_t)o * HWs + hw] = acc[r] + bias;
        }
    }
}

extern "C" void kernel_launch(void* const* d_in, const int* in_sizes, int n_in,
                              void* d_out, int out_size, void* d_ws, size_t ws_size,
                              hipStream_t stream)
{
    const float* mask      = (const float*)d_in[0];
    const float* match     = (const float*)d_in[1];
    const float* context   = (const float*)d_in[2];
    const float* geometric = (const float*)d_in[3];
    const float* anc_c     = (const float*)d_in[4];
    const float* anc_g     = (const float*)d_in[5];
    const float* ln_g  = (const float*)d_in[6];
    const float* ln_b  = (const float*)d_in[7];
    const float* lnc_g = (const float*)d_in[8];
    const float* lnc_b = (const float*)d_in[9];
    const float* lng_g = (const float*)d_in[10];
    const float* lng_b = (const float*)d_in[11];
    const float* wc_w  = (const float*)d_in[12];
    const float* wc_b  = (const float*)d_in[13];
    const float* wg_w  = (const float*)d_in[14];
    const float* wg_b  = (const float*)d_in[15];
    const float* vc_w  = (const float*)d_in[16];
    const float* vc_b  = (const float*)d_in[17];
    const float* vg_w  = (const float*)d_in[18];
    const float* vg_b  = (const float*)d_in[19];
    const float* out_w = (const float*)d_in[20];
    const float* out_b = (const float*)d_in[21];
    const float* kpc_w = (const float*)d_in[22];
    const float* kpc_b = (const float*)d_in[23];
    const float* kpg_w = (const float*)d_in[24];
    const float* kpg_b = (const float*)d_in[25];

    // All scratch in d_ws (ws_size ~256 MiB per harness fill counters; we use ~37.4 MB).
    char* w = (char*)d_ws;
    bf16*  ctx_val  = (bf16*)(w);                    //  6,553,600 B
    bf16*  geo_val  = (bf16*)(w + 6553600);          //  6,553,600 B
    bf16*  wts_g    = (bf16*)(w + 13107200);         //  7,372,800 B
    float* coords_g = (float*)(w + 20480000);        //  3,686,400 B
    bf16*  aggf     = (bf16*)(w + 24166400);         // 13,107,200 B

    float* outp = (float*)d_out;
    float* kp_out = outp + (size_t)2 * 128 * HWs;    // outputs are f32 (ref dtype)

    k_stage1<<<2400, 256, 0, stream>>>(match, context, geometric,
                                       ln_g, ln_b, lnc_g, lnc_b, lng_g, lng_b,
                                       vc_w, vc_b, vg_w, vg_b,
                                       wc_w, wc_b, wg_w, wg_b,
                                       kpc_w, kpc_b, kpg_w, kpg_b,
                                       anc_c, anc_g,
                                       ctx_val, geo_val, wts_g, coords_g, kp_out);
    k_agg<<<3200, 256, 0, stream>>>(ctx_val, geo_val, wts_g, coords_g, mask, aggf);
    k_gemm_out<<<800, 256, 0, stream>>>(aggf, out_w, out_b, outp);
}

// Round 9
// 222.152 us; speedup vs baseline: 2.5915x; 1.0742x over previous
//
#include <hip/hip_runtime.h>
#include <hip/hip_bf16.h>

typedef __hip_bfloat16 bf16;
typedef __bf16 b16x8 __attribute__((ext_vector_type(8)));
typedef float f32x4 __attribute__((ext_vector_type(4)));

#define HWs   12800   // 80*160
#define NPIX  25600   // 2*80*160
#define IMG_H 80
#define IMG_W 160

// bf16 weight-cache element offsets inside wbuf
#define OFF_VCB  0        // 128x128
#define OFF_VGB  16384    // 128x128
#define OFF_MATB 32768    // 162x128  (wc|wg|kpc|kpg concatenated)
#define OFF_OUTB 53504    // 128x256
#define NW_BF16  86272

// ---------------- k_prep: f32 -> bf16 weight cache + concatenated bias ----------------
__global__ __launch_bounds__(256) void k_prep(
    const float* __restrict__ vc_w, const float* __restrict__ vg_w,
    const float* __restrict__ wc_w, const float* __restrict__ wg_w,
    const float* __restrict__ kpc_w, const float* __restrict__ kpg_w,
    const float* __restrict__ out_w,
    const float* __restrict__ wc_b, const float* __restrict__ wg_b,
    const float* __restrict__ kpc_b, const float* __restrict__ kpg_b,
    bf16* __restrict__ wbuf, float* __restrict__ bias176)
{
    int i = blockIdx.x * 256 + threadIdx.x;
    if (i < 16384) {
        wbuf[i] = __float2bfloat16(vc_w[i]);
    } else if (i < 32768) {
        wbuf[i] = __float2bfloat16(vg_w[i - 16384]);
    } else if (i < 53504) {
        int j = i - 32768; int row = j >> 7; int c = j & 127;
        float v;
        if (row < 72)       v = wc_w[row * 128 + c];
        else if (row < 144) v = wg_w[(row - 72) * 128 + c];
        else if (row < 153) v = kpc_w[(row - 144) * 128 + c];
        else                v = kpg_w[(row - 153) * 128 + c];
        wbuf[i] = __float2bfloat16(v);
    } else if (i < NW_BF16) {
        wbuf[i] = __float2bfloat16(out_w[i - 53504]);
    } else if (i < NW_BF16 + 176) {
        int j = i - NW_BF16;
        float v = 0.f;
        if (j < 72)       v = wc_b[j];
        else if (j < 144) v = wg_b[j - 72];
        else if (j < 153) v = kpc_b[j - 144];
        else if (j < 162) v = kpg_b[j - 153];
        bias176[j] = v;
    }
}

// ---------------- Stage 1: fused LN + GEMMs, with weight prefetch overlap ----------------
// blocks [0,800): context+vc ; [800,1600): geometric+vg ; [1600,2400): match branch.
__global__ __launch_bounds__(256) void k_stage1(
    const float* __restrict__ match, const float* __restrict__ context, const float* __restrict__ geometric,
    const float* __restrict__ ln_g, const float* __restrict__ ln_b,
    const float* __restrict__ lnc_g, const float* __restrict__ lnc_b,
    const float* __restrict__ lng_g, const float* __restrict__ lng_b,
    const float* __restrict__ vc_b, const float* __restrict__ vg_b,
    const bf16* __restrict__ wbuf, const float* __restrict__ bias176,
    const float* __restrict__ anc_c, const float* __restrict__ anc_g,
    bf16* __restrict__ ctx_val, bf16* __restrict__ geo_val,
    bf16* __restrict__ wts_g, float* __restrict__ coords_g,
    float* __restrict__ kp_out)
{
    __shared__ __align__(16) bf16 tile_s[32 * 136];
    __shared__ bf16 logit_s[32 * 144];
    __shared__ float offs_s[32 * 18];
    __shared__ float red1[8][32];
    __shared__ float red2[8][32];

    int bx = blockIdx.x;
    int seg = bx / 800;                  // 0 ctx, 1 geo, 2 match
    int tile = bx - seg * 800;
    int t = threadIdx.x;
    int pixbase = tile * 32;

    const float* X  = (seg == 0) ? context : (seg == 1) ? geometric : match;
    const float* gg = (seg == 0) ? lnc_g   : (seg == 1) ? lng_g     : ln_g;
    const float* bb = (seg == 0) ? lnc_b   : (seg == 1) ? lng_b     : ln_b;

    // ---- issue LN global loads FIRST (oldest in vmcnt queue) ----
    int p = t & 31;
    int cq = t >> 5;
    int b = pixbase >= HWs;
    int hw = pixbase - b * HWs;
    const float* base = X + ((size_t)b * 128) * HWs + hw + p;
    float xv[16];
#pragma unroll
    for (int j = 0; j < 16; j++) xv[j] = base[(size_t)(cq * 16 + j) * HWs];

    // ---- prefetch this wave's B-fragments (independent of LN; drains later) ----
    int wv = t >> 6;
    int lane = t & 63;
    int s = wv >> 1;                     // subtile of 16 pixels
    int h = wv & 1;                      // output-tile parity
    int lrow = lane & 15;
    int lq = lane >> 4;
    const bf16* Wb = (seg == 0) ? wbuf + OFF_VCB
                   : (seg == 1) ? wbuf + OFF_VGB
                                : wbuf + OFF_MATB;
    b16x8 wf[4][4];
    float bpre[4];
#pragma unroll
    for (int i = 0; i < 4; i++) {
        int o = (h + 2 * i) * 16 + lrow;            // match: o <= 111 < 162, safe
        const bf16* wr = Wb + (size_t)o * 128;
#pragma unroll
        for (int kk = 0; kk < 4; kk++)
            wf[i][kk] = *(const b16x8*)(wr + (kk * 4 + lq) * 8);
        bpre[i] = (seg == 0) ? vc_b[o] : (seg == 1) ? vg_b[o] : bias176[o];
    }

    // ---- LN reduce + normalized tile (waits only on LN loads) ----
    {
        float s1 = 0.f, s2 = 0.f;
#pragma unroll
        for (int j = 0; j < 16; j++) { s1 += xv[j]; s2 += xv[j] * xv[j]; }
        red1[cq][p] = s1; red2[cq][p] = s2;
        __syncthreads();
        float S1 = 0.f, S2 = 0.f;
#pragma unroll
        for (int q = 0; q < 8; q++) { S1 += red1[q][p]; S2 += red2[q][p]; }
        float mean = S1 * (1.f / 128.f);
        float var  = fmaxf(S2 * (1.f / 128.f) - mean * mean, 0.f);
        float rstd = rsqrtf(var + 1e-5f);
#pragma unroll
        for (int j = 0; j < 16; j++) {
            int c = cq * 16 + j;
            float y = (xv[j] - mean) * rstd * gg[c] + bb[c];
            tile_s[p * 136 + c] = __float2bfloat16(y);
        }
        __syncthreads();
    }

    // ---- A fragments ----
    const b16x8* arow = (const b16x8*)(tile_s + (s * 16 + lrow) * 136);
    b16x8 af[4];
#pragma unroll
    for (int kk = 0; kk < 4; kk++) af[kk] = arow[kk * 4 + lq];

    if (seg < 2) {
        bf16* val = (seg == 0) ? ctx_val : geo_val;
#pragma unroll
        for (int i = 0; i < 4; i++) {
            int o = (h + 2 * i) * 16 + lrow;
            f32x4 acc = {0.f, 0.f, 0.f, 0.f};
#pragma unroll
            for (int kk = 0; kk < 4; kk++)
                acc = __builtin_amdgcn_mfma_f32_16x16x32_bf16(af[kk], wf[i][kk], acc, 0, 0, 0);
#pragma unroll
            for (int r = 0; r < 4; r++) {
                int pix = pixbase + s * 16 + lq * 4 + r;   // C/D: row = lq*4+r, col = lrow
                val[(size_t)pix * 128 + o] = __float2bfloat16(acc[r] + bpre[i]);
            }
        }
        return;
    }

    // ---- seg == 2: match branch. Prefetched ots (o <= 111 -> all logits) ----
#pragma unroll
    for (int i = 0; i < 4; i++) {
        int o = (h + 2 * i) * 16 + lrow;
        f32x4 acc = {0.f, 0.f, 0.f, 0.f};
#pragma unroll
        for (int kk = 0; kk < 4; kk++)
            acc = __builtin_amdgcn_mfma_f32_16x16x32_bf16(af[kk], wf[i][kk], acc, 0, 0, 0);
#pragma unroll
        for (int r = 0; r < 4; r++) {
            int row = s * 16 + lq * 4 + r;
            logit_s[row * 144 + o] = __float2bfloat16(acc[r] + bpre[i]);
        }
    }
    // remaining ots (h=0: 8,10 ; h=1: 9), loaded inline
    for (int ot = h + 8; ot < 11; ot += 2) {
        int o = ot * 16 + lrow;                     // up to 175; wbuf/bias176 padded
        const bf16* wr = Wb + (size_t)o * 128;
        f32x4 acc = {0.f, 0.f, 0.f, 0.f};
#pragma unroll
        for (int kk = 0; kk < 4; kk++)
            acc = __builtin_amdgcn_mfma_f32_16x16x32_bf16(af[kk], *(const b16x8*)(wr + (kk * 4 + lq) * 8), acc, 0, 0, 0);
        float bias = bias176[o];
#pragma unroll
        for (int r = 0; r < 4; r++) {
            int row = s * 16 + lq * 4 + r;
            float v = acc[r] + bias;
            if (o < 144)       logit_s[row * 144 + o] = __float2bfloat16(v);
            else if (o < 162)  offs_s[row * 18 + (o - 144)] = v;
        }
    }
    __syncthreads();

    // softmax over P per (pixel, branch, group): 512 tasks
#pragma unroll
    for (int i = 0; i < 2; i++) {
        int task = t + 256 * i;
        int lp = task >> 4;
        int sub = task & 15;
        int br = sub >> 3;
        int g = sub & 7;
        const bf16* basel = logit_s + lp * 144 + br * 72 + g;   // channel c = p*8+g
        float v[9];
        float m = -1e30f;
#pragma unroll
        for (int pp = 0; pp < 9; pp++) { v[pp] = __bfloat162float(basel[pp * 8]); m = fmaxf(m, v[pp]); }
        float ssum = 0.f;
#pragma unroll
        for (int pp = 0; pp < 9; pp++) { v[pp] = __expf(v[pp] - m); ssum += v[pp]; }
        float inv = 1.f / ssum;
        int pix = pixbase + lp;
        bf16* wbp = wts_g + ((size_t)pix * 2 + br) * 72 + g * 9;
#pragma unroll
        for (int pp = 0; pp < 9; pp++) wbp[pp] = __float2bfloat16(v[pp] * inv);
    }

    // keypoints + sample coords: 576 tasks (kp_out is f32, the reference dtype)
    for (int i = 0; i < 3; i++) {
        int task = t + 256 * i;
        if (task < 576) {
            int lp = task / 18;
            int sub = task - lp * 18;
            int br = sub / 9;
            int pp = sub - br * 9;
            int pix = pixbase + lp;
            float off = offs_s[lp * 18 + br * 9 + pp];
            const float* anc = br ? anc_g : anc_c;
            float ax = anc[(size_t)pix * 18 + pp * 2];
            float ay = anc[(size_t)pix * 18 + pp * 2 + 1];
            float kx = ax + off;
            float* kpo = kp_out + (size_t)br * (NPIX * 18) + (size_t)pix * 18 + pp * 2;
            kpo[0] = kx;
            kpo[1] = ay;
            float* cbp = coords_g + ((size_t)pix * 2 + br) * 18 + pp * 2;
            cbp[0] = kx * 160.f - 0.5f;
            cbp[1] = ay * 80.f - 0.5f;
        }
    }
}

// ---------------- fused bilinear gather + aggregate + final projection ----------------
// 800 blocks x 32 pixels. Phase 1: 64 (pixel,branch) tasks in 4 rounds of 16
// concurrent quarter-wave tasks (lane owns 8 channels, b16x8 gathers).
// Phase 2: MFMA projection K=256 from LDS (pitch 264), transposed f32 store.
__global__ __launch_bounds__(256) void k_aggout(
    const bf16* __restrict__ ctx_val, const bf16* __restrict__ geo_val,
    const bf16* __restrict__ wts_g, const float* __restrict__ coords_g,
    const float* __restrict__ mask,
    const bf16* __restrict__ outb, const float* __restrict__ out_b,
    float* __restrict__ out)
{
    __shared__ __align__(16) bf16 smem[32 * 264];
    int t = threadIdx.x;
    int wv = t >> 6;
    int lane = t & 63;
    int q = lane >> 4;            // quarter-wave slot
    int sub = lane & 15;          // channel octet
    int c0 = sub * 8;
    int g = sub >> 1;             // group = c/16
    int pixbase = blockIdx.x * 32;
    int b = pixbase >= HWs;       // uniform per block
    int rowbase = b * HWs;
    int qwid = wv * 4 + q;

    for (int i = 0; i < 4; i++) {
        int task = i * 16 + qwid;         // 0..63
        int lp = task >> 1;
        int br = task & 1;
        int pix = pixbase + lp;
        int tk = pix * 2 + br;
        const bf16* val = br ? geo_val : ctx_val;
        const float* cb = coords_g + (size_t)tk * 18;
        const bf16* wb = wts_g + (size_t)tk * 72 + g * 9;
        float wtv[9];
#pragma unroll
        for (int pp = 0; pp < 9; pp++) wtv[pp] = __bfloat162float(wb[pp]);
        float acc[8] = {0.f, 0.f, 0.f, 0.f, 0.f, 0.f, 0.f, 0.f};
        for (int pp = 0; pp < 9; pp++) {
            float px = cb[pp * 2];
            float py = cb[pp * 2 + 1];
            float fx = floorf(px), fy = floorf(py);
            float dx = px - fx, dy = py - fy;
            int x0 = (int)fx, y0 = (int)fy;
            float wt = wtv[pp];
#pragma unroll
            for (int c4 = 0; c4 < 4; c4++) {
                int xi = x0 + (c4 & 1);
                int yi = y0 + (c4 >> 1);
                bool ok = (xi >= 0) & (xi < IMG_W) & (yi >= 0) & (yi < IMG_H);
                int xc = min(max(xi, 0), IMG_W - 1);
                int yc = min(max(yi, 0), IMG_H - 1);
                float wx = (c4 & 1) ? dx : 1.f - dx;
                float wy = (c4 >> 1) ? dy : 1.f - dy;
                float wgt = ok ? wx * wy * wt : 0.f;
                b16x8 v = *(const b16x8*)(val + (size_t)(rowbase + yc * IMG_W + xc) * 128 + c0);
#pragma unroll
                for (int j = 0; j < 8; j++) acc[j] += wgt * (float)v[j];
            }
        }
        float mv = (br == 0) ? mask[pix] : 1.f;
        b16x8 pk;
#pragma unroll
        for (int j = 0; j < 8; j++) pk[j] = (__bf16)(acc[j] * mv);
        *(b16x8*)(smem + lp * 264 + br * 128 + c0) = pk;
    }
    __syncthreads();

    // ---- phase 2: projection (K=256) ----
    int s = wv >> 1;
    int h = wv & 1;
    int lrow = lane & 15;
    int lq = lane >> 4;
    const b16x8* arow = (const b16x8*)(smem + (s * 16 + lrow) * 264);
    b16x8 af[8];
#pragma unroll
    for (int kk = 0; kk < 8; kk++) af[kk] = arow[kk * 4 + lq];
#pragma unroll
    for (int i = 0; i < 4; i++) {
        int o = (h + 2 * i) * 16 + lrow;
        const bf16* wrow = outb + (size_t)o * 256;
        f32x4 acc = {0.f, 0.f, 0.f, 0.f};
#pragma unroll
        for (int kk = 0; kk < 8; kk++)
            acc = __builtin_amdgcn_mfma_f32_16x16x32_bf16(af[kk], *(const b16x8*)(wrow + (kk * 4 + lq) * 8), acc, 0, 0, 0);
        float bias = out_b[o];
#pragma unroll
        for (int r = 0; r < 4; r++) {
            int pix = pixbase + s * 16 + lq * 4 + r;
            int hw = pix - b * HWs;
            out[(size_t)b * (128 * HWs) + (size_t)o * HWs + hw] = acc[r] + bias;
        }
    }
}

extern "C" void kernel_launch(void* const* d_in, const int* in_sizes, int n_in,
                              void* d_out, int out_size, void* d_ws, size_t ws_size,
                              hipStream_t stream)
{
    const float* mask      = (const float*)d_in[0];
    const float* match     = (const float*)d_in[1];
    const float* context   = (const float*)d_in[2];
    const float* geometric = (const float*)d_in[3];
    const float* anc_c     = (const float*)d_in[4];
    const float* anc_g     = (const float*)d_in[5];
    const float* ln_g  = (const float*)d_in[6];
    const float* ln_b  = (const float*)d_in[7];
    const float* lnc_g = (const float*)d_in[8];
    const float* lnc_b = (const float*)d_in[9];
    const float* lng_g = (const float*)d_in[10];
    const float* lng_b = (const float*)d_in[11];
    const float* wc_w  = (const float*)d_in[12];
    const float* wc_b  = (const float*)d_in[13];
    const float* wg_w  = (const float*)d_in[14];
    const float* wg_b  = (const float*)d_in[15];
    const float* vc_w  = (const float*)d_in[16];
    const float* vc_b  = (const float*)d_in[17];
    const float* vg_w  = (const float*)d_in[18];
    const float* vg_b  = (const float*)d_in[19];
    const float* out_w = (const float*)d_in[20];
    const float* out_b = (const float*)d_in[21];
    const float* kpc_w = (const float*)d_in[22];
    const float* kpc_b = (const float*)d_in[23];
    const float* kpg_w = (const float*)d_in[24];
    const float* kpg_b = (const float*)d_in[25];

    // d_ws layout (~24.3 MB of the workspace)
    char* w = (char*)d_ws;
    bf16*  ctx_val  = (bf16*)(w);                    //  6,553,600 B
    bf16*  geo_val  = (bf16*)(w + 6553600);          //  6,553,600 B
    bf16*  wts_g    = (bf16*)(w + 13107200);         //  7,372,800 B
    float* coords_g = (float*)(w + 20480000);        //  3,686,400 B
    bf16*  wbuf     = (bf16*)(w + 24166400);         //    172,544 B
    float* bias176  = (float*)(w + 24338944);        //        704 B

    float* outp = (float*)d_out;
    float* kp_out = outp + (size_t)2 * 128 * HWs;    // outputs are f32 (ref dtype)

    k_prep<<<(NW_BF16 + 176 + 255) / 256, 256, 0, stream>>>(
        vc_w, vg_w, wc_w, wg_w, kpc_w, kpg_w, out_w,
        wc_b, wg_b, kpc_b, kpg_b, wbuf, bias176);
    k_stage1<<<2400, 256, 0, stream>>>(match, context, geometric,
                                       ln_g, ln_b, lnc_g, lnc_b, lng_g, lng_b,
                                       vc_b, vg_b, wbuf, bias176,
                                       anc_c, anc_g,
                                       ctx_val, geo_val, wts_g, coords_g, kp_out);
    k_aggout<<<800, 256, 0, stream>>>(ctx_val, geo_val, wts_g, coords_g, mask,
                                      wbuf + OFF_OUTB, out_b, outp);
}

// Round 10
// 203.566 us; speedup vs baseline: 2.8281x; 1.0913x over previous
//
#include <hip/hip_runtime.h>
#include <hip/hip_bf16.h>

typedef __hip_bfloat16 bf16;
typedef __bf16 b16x8 __attribute__((ext_vector_type(8)));
typedef float f32x4 __attribute__((ext_vector_type(4)));
typedef float f32x2 __attribute__((ext_vector_type(2)));

#define HWs   12800   // 80*160
#define NPIX  25600   // 2*80*160
#define IMG_H 80
#define IMG_W 160

// bf16 weight-cache element offsets inside wbuf
#define OFF_VCB  0        // 128x128
#define OFF_VGB  16384    // 128x128
#define OFF_MATB 32768    // 162x128  (wc|wg|kpc|kpg concatenated; +pad rows into OUTB, reads guarded)
#define OFF_OUTB 53504    // 128x256
#define NW_BF16  86272

// fp8 e4m3 (OCP, gfx950-native) encode one float -> byte
static __device__ inline unsigned char enc_fp8(float v)
{
    return (unsigned char)(__builtin_amdgcn_cvt_pk_fp8_f32(v, v, 0, false) & 0xFF);
}

// ---------------- k_prep: f32 -> bf16 weight cache + concatenated bias ----------------
__global__ __launch_bounds__(256) void k_prep(
    const float* __restrict__ vc_w, const float* __restrict__ vg_w,
    const float* __restrict__ wc_w, const float* __restrict__ wg_w,
    const float* __restrict__ kpc_w, const float* __restrict__ kpg_w,
    const float* __restrict__ out_w,
    const float* __restrict__ wc_b, const float* __restrict__ wg_b,
    const float* __restrict__ kpc_b, const float* __restrict__ kpg_b,
    bf16* __restrict__ wbuf, float* __restrict__ bias176)
{
    int i = blockIdx.x * 256 + threadIdx.x;
    if (i < 16384) {
        wbuf[i] = __float2bfloat16(vc_w[i]);
    } else if (i < 32768) {
        wbuf[i] = __float2bfloat16(vg_w[i - 16384]);
    } else if (i < 53504) {
        int j = i - 32768; int row = j >> 7; int c = j & 127;
        float v;
        if (row < 72)       v = wc_w[row * 128 + c];
        else if (row < 144) v = wg_w[(row - 72) * 128 + c];
        else if (row < 153) v = kpc_w[(row - 144) * 128 + c];
        else                v = kpg_w[(row - 153) * 128 + c];
        wbuf[i] = __float2bfloat16(v);
    } else if (i < NW_BF16) {
        wbuf[i] = __float2bfloat16(out_w[i - 53504]);
    } else if (i < NW_BF16 + 176) {
        int j = i - NW_BF16;
        float v = 0.f;
        if (j < 72)       v = wc_b[j];
        else if (j < 144) v = wg_b[j - 72];
        else if (j < 153) v = kpc_b[j - 144];
        else if (j < 162) v = kpg_b[j - 153];
        bias176[j] = v;
    }
}

// ---------------- Stage 1: fused LN + GEMMs, weight prefetch overlap ----------------
// blocks [0,800): context+vc -> ctx8 (fp8) ; [800,1600): geometric+vg -> geo8 ;
// [1600,2400): match branch -> softmax wts, coords, kp_out.
__global__ __launch_bounds__(256) void k_stage1(
    const float* __restrict__ match, const float* __restrict__ context, const float* __restrict__ geometric,
    const float* __restrict__ ln_g, const float* __restrict__ ln_b,
    const float* __restrict__ lnc_g, const float* __restrict__ lnc_b,
    const float* __restrict__ lng_g, const float* __restrict__ lng_b,
    const float* __restrict__ vc_b, const float* __restrict__ vg_b,
    const bf16* __restrict__ wbuf, const float* __restrict__ bias176,
    const float* __restrict__ anc_c, const float* __restrict__ anc_g,
    unsigned char* __restrict__ ctx8, unsigned char* __restrict__ geo8,
    bf16* __restrict__ wts_g, float* __restrict__ coords_g,
    float* __restrict__ kp_out)
{
    __shared__ __align__(16) bf16 tile_s[32 * 136];
    __shared__ bf16 logit_s[32 * 144];
    __shared__ float offs_s[32 * 18];
    __shared__ float red1[8][32];
    __shared__ float red2[8][32];

    int bx = blockIdx.x;
    int seg = bx / 800;                  // 0 ctx, 1 geo, 2 match
    int tile = bx - seg * 800;
    int t = threadIdx.x;
    int pixbase = tile * 32;

    const float* X  = (seg == 0) ? context : (seg == 1) ? geometric : match;
    const float* gg = (seg == 0) ? lnc_g   : (seg == 1) ? lng_g     : ln_g;
    const float* bb = (seg == 0) ? lnc_b   : (seg == 1) ? lng_b     : ln_b;

    // ---- issue LN global loads FIRST (oldest in vmcnt queue) ----
    int p = t & 31;
    int cq = t >> 5;
    int b = pixbase >= HWs;
    int hw = pixbase - b * HWs;
    const float* base = X + ((size_t)b * 128) * HWs + hw + p;
    float xv[16];
#pragma unroll
    for (int j = 0; j < 16; j++) xv[j] = base[(size_t)(cq * 16 + j) * HWs];

    // ---- prefetch this wave's B-fragments (independent of LN) ----
    int wv = t >> 6;
    int lane = t & 63;
    int s = wv >> 1;                     // subtile of 16 pixels
    int h = wv & 1;                      // output-tile parity
    int lrow = lane & 15;
    int lq = lane >> 4;
    const bf16* Wb = (seg == 0) ? wbuf + OFF_VCB
                   : (seg == 1) ? wbuf + OFF_VGB
                                : wbuf + OFF_MATB;
    b16x8 wf[4][4];
    float bpre[4];
#pragma unroll
    for (int i = 0; i < 4; i++) {
        int o = (h + 2 * i) * 16 + lrow;            // match: o <= 111 < 162, safe
        const bf16* wr = Wb + (size_t)o * 128;
#pragma unroll
        for (int kk = 0; kk < 4; kk++)
            wf[i][kk] = *(const b16x8*)(wr + (kk * 4 + lq) * 8);
        bpre[i] = (seg == 0) ? vc_b[o] : (seg == 1) ? vg_b[o] : bias176[o];
    }

    // ---- LN reduce + normalized tile ----
    {
        float s1 = 0.f, s2 = 0.f;
#pragma unroll
        for (int j = 0; j < 16; j++) { s1 += xv[j]; s2 += xv[j] * xv[j]; }
        red1[cq][p] = s1; red2[cq][p] = s2;
        __syncthreads();
        float S1 = 0.f, S2 = 0.f;
#pragma unroll
        for (int q = 0; q < 8; q++) { S1 += red1[q][p]; S2 += red2[q][p]; }
        float mean = S1 * (1.f / 128.f);
        float var  = fmaxf(S2 * (1.f / 128.f) - mean * mean, 0.f);
        float rstd = rsqrtf(var + 1e-5f);
#pragma unroll
        for (int j = 0; j < 16; j++) {
            int c = cq * 16 + j;
            float y = (xv[j] - mean) * rstd * gg[c] + bb[c];
            tile_s[p * 136 + c] = __float2bfloat16(y);
        }
        __syncthreads();
    }

    // ---- A fragments ----
    const b16x8* arow = (const b16x8*)(tile_s + (s * 16 + lrow) * 136);
    b16x8 af[4];
#pragma unroll
    for (int kk = 0; kk < 4; kk++) af[kk] = arow[kk * 4 + lq];

    if (seg < 2) {
        unsigned char* val = (seg == 0) ? ctx8 : geo8;
#pragma unroll
        for (int i = 0; i < 4; i++) {
            int o = (h + 2 * i) * 16 + lrow;
            f32x4 acc = {0.f, 0.f, 0.f, 0.f};
#pragma unroll
            for (int kk = 0; kk < 4; kk++)
                acc = __builtin_amdgcn_mfma_f32_16x16x32_bf16(af[kk], wf[i][kk], acc, 0, 0, 0);
#pragma unroll
            for (int r = 0; r < 4; r++) {
                int pix = pixbase + s * 16 + lq * 4 + r;   // C/D: row = lq*4+r, col = lrow
                val[(size_t)pix * 128 + o] = enc_fp8(acc[r] + bpre[i]);
            }
        }
        return;
    }

    // ---- seg == 2: match branch ----
#pragma unroll
    for (int i = 0; i < 4; i++) {
        int o = (h + 2 * i) * 16 + lrow;
        f32x4 acc = {0.f, 0.f, 0.f, 0.f};
#pragma unroll
        for (int kk = 0; kk < 4; kk++)
            acc = __builtin_amdgcn_mfma_f32_16x16x32_bf16(af[kk], wf[i][kk], acc, 0, 0, 0);
#pragma unroll
        for (int r = 0; r < 4; r++) {
            int row = s * 16 + lq * 4 + r;
            logit_s[row * 144 + o] = __float2bfloat16(acc[r] + bpre[i]);
        }
    }
    for (int ot = h + 8; ot < 11; ot += 2) {        // h=0: 8,10 ; h=1: 9
        int o = ot * 16 + lrow;                     // up to 175; reads padded, stores guarded
        const bf16* wr = Wb + (size_t)o * 128;
        f32x4 acc = {0.f, 0.f, 0.f, 0.f};
#pragma unroll
        for (int kk = 0; kk < 4; kk++)
            acc = __builtin_amdgcn_mfma_f32_16x16x32_bf16(af[kk], *(const b16x8*)(wr + (kk * 4 + lq) * 8), acc, 0, 0, 0);
        float bias = bias176[o];
#pragma unroll
        for (int r = 0; r < 4; r++) {
            int row = s * 16 + lq * 4 + r;
            float v = acc[r] + bias;
            if (o < 144)       logit_s[row * 144 + o] = __float2bfloat16(v);
            else if (o < 162)  offs_s[row * 18 + (o - 144)] = v;
        }
    }
    __syncthreads();

    // softmax over P per (pixel, branch, group): 512 tasks
#pragma unroll
    for (int i = 0; i < 2; i++) {
        int task = t + 256 * i;
        int lp = task >> 4;
        int sub = task & 15;
        int br = sub >> 3;
        int g = sub & 7;
        const bf16* basel = logit_s + lp * 144 + br * 72 + g;   // channel c = p*8+g
        float v[9];
        float m = -1e30f;
#pragma unroll
        for (int pp = 0; pp < 9; pp++) { v[pp] = __bfloat162float(basel[pp * 8]); m = fmaxf(m, v[pp]); }
        float ssum = 0.f;
#pragma unroll
        for (int pp = 0; pp < 9; pp++) { v[pp] = __expf(v[pp] - m); ssum += v[pp]; }
        float inv = 1.f / ssum;
        int pix = pixbase + lp;
        bf16* wbp = wts_g + ((size_t)pix * 2 + br) * 72 + g * 9;
#pragma unroll
        for (int pp = 0; pp < 9; pp++) wbp[pp] = __float2bfloat16(v[pp] * inv);
    }

    // keypoints + sample coords: 576 tasks (kp_out f32 = ref output dtype)
    for (int i = 0; i < 3; i++) {
        int task = t + 256 * i;
        if (task < 576) {
            int lp = task / 18;
            int sub = task - lp * 18;
            int br = sub / 9;
            int pp = sub - br * 9;
            int pix = pixbase + lp;
            float off = offs_s[lp * 18 + br * 9 + pp];
            const float* anc = br ? anc_g : anc_c;
            float ax = anc[(size_t)pix * 18 + pp * 2];
            float ay = anc[(size_t)pix * 18 + pp * 2 + 1];
            float kx = ax + off;
            float* kpo = kp_out + (size_t)br * (NPIX * 18) + (size_t)pix * 18 + pp * 2;
            kpo[0] = kx;
            kpo[1] = ay;
            float* cbp = coords_g + ((size_t)pix * 2 + br) * 18 + pp * 2;
            cbp[0] = kx * 160.f - 0.5f;
            cbp[1] = ay * 80.f - 0.5f;
        }
    }
}

// ---------------- bilinear gather (fp8) + aggregate, XCD-partitioned by branch ----------------
// Quarter-wave (16 lanes) per (pixel,branch) task; lane owns 8 channels (8 B fp8).
// blockIdx&7 ~ XCD (round-robin dispatch heuristic): XCDs 0-3 -> ctx, 4-7 -> geo,
// so each per-XCD L2 holds ONE 3.28 MB fp8 map. 3200 blocks x 16 tasks.
__global__ __launch_bounds__(256) void k_agg(
    const unsigned char* __restrict__ ctx8, const unsigned char* __restrict__ geo8,
    const bf16* __restrict__ wts_g, const float* __restrict__ coords_g,
    const float* __restrict__ mask,
    bf16* __restrict__ aggf)
{
    int t = threadIdx.x;
    int wv = t >> 6;
    int lane = t & 63;
    int q = lane >> 4;           // quarter-wave task slot
    int sub = lane & 15;         // channel octet
    int c0 = sub * 8;
    int g = sub >> 1;            // group = c/16

    int bx = blockIdx.x;         // 0..3199
    int xcd = bx & 7;
    int br = xcd >> 2;           // XCDs 0-3 -> ctx, 4-7 -> geo
    int grp = (bx >> 3) * 4 + (xcd & 3);      // 0..1599
    int pix = grp * 16 + wv * 4 + q;          // 0..25599
    int tk = pix * 2 + br;
    int b = pix >= HWs;
    int rowbase = b * HWs;

    const unsigned char* val = br ? geo8 : ctx8;
    const float* cb = coords_g + (size_t)tk * 18;
    const bf16* wb = wts_g + (size_t)tk * 72 + g * 9;

    float wtv[9];
#pragma unroll
    for (int pp = 0; pp < 9; pp++) wtv[pp] = __bfloat162float(wb[pp]);

    float acc[8] = {0.f, 0.f, 0.f, 0.f, 0.f, 0.f, 0.f, 0.f};
    for (int pp = 0; pp < 9; pp++) {
        float px = cb[pp * 2];
        float py = cb[pp * 2 + 1];
        float fx = floorf(px), fy = floorf(py);
        float dx = px - fx, dy = py - fy;
        int x0 = (int)fx, y0 = (int)fy;
        float wt = wtv[pp];
#pragma unroll
        for (int c4 = 0; c4 < 4; c4++) {
            int xi = x0 + (c4 & 1);
            int yi = y0 + (c4 >> 1);
            bool ok = (xi >= 0) & (xi < IMG_W) & (yi >= 0) & (yi < IMG_H);
            int xc = min(max(xi, 0), IMG_W - 1);
            int yc = min(max(yi, 0), IMG_H - 1);
            float wx = (c4 & 1) ? dx : 1.f - dx;
            float wy = (c4 >> 1) ? dy : 1.f - dy;
            float wgt = ok ? wx * wy * wt : 0.f;
            uint2 u = *(const uint2*)(val + (size_t)(rowbase + yc * IMG_W + xc) * 128 + c0);
            f32x2 v01 = __builtin_amdgcn_cvt_pk_f32_fp8(u.x, false);
            f32x2 v23 = __builtin_amdgcn_cvt_pk_f32_fp8(u.x, true);
            f32x2 v45 = __builtin_amdgcn_cvt_pk_f32_fp8(u.y, false);
            f32x2 v67 = __builtin_amdgcn_cvt_pk_f32_fp8(u.y, true);
            acc[0] += wgt * v01[0]; acc[1] += wgt * v01[1];
            acc[2] += wgt * v23[0]; acc[3] += wgt * v23[1];
            acc[4] += wgt * v45[0]; acc[5] += wgt * v45[1];
            acc[6] += wgt * v67[0]; acc[7] += wgt * v67[1];
        }
    }
    float mv = (br == 0) ? mask[pix] : 1.f;
    b16x8 pk;
#pragma unroll
    for (int j = 0; j < 8; j++) pk[j] = (__bf16)(acc[j] * mv);
    *(b16x8*)(aggf + (size_t)pix * 256 + br * 128 + c0) = pk;
}

// ---------------- final projection (MFMA, K=256) + transposed f32 store ----------------
__global__ __launch_bounds__(256) void k_out(
    const bf16* __restrict__ aggf,
    const bf16* __restrict__ outb, const float* __restrict__ out_b,
    float* __restrict__ out)
{
    int t = threadIdx.x;
    int pixbase = blockIdx.x * 32;       // 800 blocks
    int wv = t >> 6;
    int lane = t & 63;
    int s = wv >> 1;
    int h = wv & 1;
    int lrow = lane & 15;
    int lq = lane >> 4;
    const b16x8* arow = (const b16x8*)(aggf + (size_t)(pixbase + s * 16 + lrow) * 256);
    b16x8 af[8];
#pragma unroll
    for (int kk = 0; kk < 8; kk++) af[kk] = arow[kk * 4 + lq];
    int b = pixbase >= HWs;
#pragma unroll
    for (int i = 0; i < 4; i++) {
        int o = (h + 2 * i) * 16 + lrow;
        const bf16* wrow = outb + (size_t)o * 256;
        f32x4 acc = {0.f, 0.f, 0.f, 0.f};
#pragma unroll
        for (int kk = 0; kk < 8; kk++)
            acc = __builtin_amdgcn_mfma_f32_16x16x32_bf16(af[kk], *(const b16x8*)(wrow + (kk * 4 + lq) * 8), acc, 0, 0, 0);
        float bias = out_b[o];
#pragma unroll
        for (int r = 0; r < 4; r++) {
            int pix = pixbase + s * 16 + lq * 4 + r;
            int hw = pix - b * HWs;
            out[(size_t)b * (128 * HWs) + (size_t)o * HWs + hw] = acc[r] + bias;
        }
    }
}

extern "C" void kernel_launch(void* const* d_in, const int* in_sizes, int n_in,
                              void* d_out, int out_size, void* d_ws, size_t ws_size,
                              hipStream_t stream)
{
    const float* mask      = (const float*)d_in[0];
    const float* match     = (const float*)d_in[1];
    const float* context   = (const float*)d_in[2];
    const float* geometric = (const float*)d_in[3];
    const float* anc_c     = (const float*)d_in[4];
    const float* anc_g     = (const float*)d_in[5];
    const float* ln_g  = (const float*)d_in[6];
    const float* ln_b  = (const float*)d_in[7];
    const float* lnc_g = (const float*)d_in[8];
    const float* lnc_b = (const float*)d_in[9];
    const float* lng_g = (const float*)d_in[10];
    const float* lng_b = (const float*)d_in[11];
    const float* wc_w  = (const float*)d_in[12];
    const float* wc_b  = (const float*)d_in[13];
    const float* wg_w  = (const float*)d_in[14];
    const float* wg_b  = (const float*)d_in[15];
    const float* vc_w  = (const float*)d_in[16];
    const float* vc_b  = (const float*)d_in[17];
    const float* vg_w  = (const float*)d_in[18];
    const float* vg_b  = (const float*)d_in[19];
    const float* out_w = (const float*)d_in[20];
    const float* out_b = (const float*)d_in[21];
    const float* kpc_w = (const float*)d_in[22];
    const float* kpc_b = (const float*)d_in[23];
    const float* kpg_w = (const float*)d_in[24];
    const float* kpg_b = (const float*)d_in[25];

    // d_ws layout
    char* w = (char*)d_ws;
    unsigned char* ctx8 = (unsigned char*)(w);       //  3,276,800 B (fp8)
    unsigned char* geo8 = (unsigned char*)(w + 3276800);  // 3,276,800 B
    bf16*  wts_g    = (bf16*)(w + 6553600);          //  7,372,800 B
    float* coords_g = (float*)(w + 13926400);        //  3,686,400 B
    bf16*  aggf     = (bf16*)(w + 17612800);         // 13,107,200 B
    bf16*  wbuf     = (bf16*)(w + 30720000);         //    172,544 B
    float* bias176  = (float*)(w + 30892544);        //        704 B

    float* outp = (float*)d_out;
    float* kp_out = outp + (size_t)2 * 128 * HWs;    // outputs are f32 (ref dtype)

    k_prep<<<(NW_BF16 + 176 + 255) / 256, 256, 0, stream>>>(
        vc_w, vg_w, wc_w, wg_w, kpc_w, kpg_w, out_w,
        wc_b, wg_b, kpc_b, kpg_b, wbuf, bias176);
    k_stage1<<<2400, 256, 0, stream>>>(match, context, geometric,
                                       ln_g, ln_b, lnc_g, lnc_b, lng_g, lng_b,
                                       vc_b, vg_b, wbuf, bias176,
                                       anc_c, anc_g,
                                       ctx8, geo8, wts_g, coords_g, kp_out);
    k_agg<<<3200, 256, 0, stream>>>(ctx8, geo8, wts_g, coords_g, mask, aggf);
    k_out<<<800, 256, 0, stream>>>(aggf, wbuf + OFF_OUTB, out_b, outp);
}